// Round 4
// baseline (597.834 us; speedup 1.0000x reference)
//
#include <hip/hip_runtime.h>

// Problem constants
constexpr int B  = 8;
constexpr int C  = 256;
constexpr int Hh = 64;
constexpr int Ww = 64;
constexpr int P  = Hh * Ww;        // 4096 pixels
constexpr int CP = C * P;          // 1,048,576 elements per (b,t) slice
constexpr int CT = 3 * C;          // 768 concat channels
constexpr int J  = B * P;          // 32768 (batch*pixel columns)

// NOTE: this version deliberately uses NO workspace (d_ws untouched) —
// testing the hypothesis that ws writes were crashing the container.

// ---------------------------------------------------------------------------
// Kernel 1: copy prev/next slices straight to output slots 0 and 1
// ---------------------------------------------------------------------------
__global__ __launch_bounds__(256) void k_copy(const float4* __restrict__ x4,
                                              float4* __restrict__ o4) {
    int tid = blockIdx.x * blockDim.x + threadIdx.x;
    const int per_b = 2 * CP / 4;        // float4 per batch for t=0,1
    const int bstr  = 3 * CP / 4;        // float4 batch stride
    if (tid < B * per_b) {
        int b = tid / per_b;
        int r = tid - b * per_b;
        o4[b * bstr + r] = x4[b * bstr + r];
    }
}

// ---------------------------------------------------------------------------
// Kernel 2: fully fused per-(batch,row) pipeline.
// One block handles the 64 pixels of image row y in batch b:
//   phase 1: inv L2 norms of prev/next features for rows clip(y-1..y+1)
//            (fp64 accumulation) -> LDS
//   phase 2: 9-neighbor cosine argmin per pixel, both sides (fp64 dots;
//            common positive 1/|cur| factor dropped -> same ordering;
//            strict < keeps first k, matching numpy argmin tie-break)
//   phase 3: 256x64 GEMM over K=768 with fused gather of the selected
//            normalized neighbor vectors; raw conv -> out slot 2
// ---------------------------------------------------------------------------
__global__ __launch_bounds__(256) void k_fused(const float* __restrict__ x,
                                               const float* __restrict__ Wg,
                                               float* __restrict__ out) {
    __shared__ double red[4][64];        // norm partial sums
    __shared__ float  inv_s[2][3][64];   // inv norms [side][row r][x]
    __shared__ int    sel_s[2][64];      // selected neighbor pixel index
    __shared__ float  sinv_s[2][64];     // its inv norm
    __shared__ __align__(16) float As[16][260];  // W tile [kc][m], pad 260
    __shared__ __align__(16) float Bs[16][68];   // feat tile [kc][j], pad 68

    const int t = threadIdx.x;
    const int b = blockIdx.x >> 6;
    const int y = blockIdx.x & 63;

    const float* prevb = x + (size_t)(b * 3 + 0) * CP;
    const float* nextb = x + (size_t)(b * 3 + 1) * CP;
    const float* curb  = x + (size_t)(b * 3 + 2) * CP;

    // ---- phase 1: inv norms for rows clip(y-1+r), r=0..2, both sides
    {
        const int px = t & 63, cq = t >> 6;   // pixel, channel-quarter
        for (int side = 0; side < 2; ++side) {
            const float* sb = side ? nextb : prevb;
            for (int r = 0; r < 3; ++r) {
                int ry = min(max(y - 1 + r, 0), Hh - 1);
                const float* src = sb + ry * Ww + px;
                double acc = 0.0;
                #pragma unroll 8
                for (int c = cq * 64; c < cq * 64 + 64; ++c) {
                    float v = src[c * P];
                    acc = fma((double)v, (double)v, acc);
                }
                red[cq][px] = acc;
                __syncthreads();
                if (cq == 0) {
                    double s = red[0][px] + red[1][px] + red[2][px] + red[3][px];
                    float nrm = (float)sqrt(s);
                    inv_s[side][r][px] = 1.0f / fmaxf(nrm, 1e-12f);
                }
                __syncthreads();
            }
        }
    }

    // ---- phase 2: per-pixel argmin over 9 clipped neighbors (128 threads)
    if (t < 128) {
        const int side = t >> 6, px = t & 63;
        const float* sb = side ? nextb : prevb;
        int   nidx[9];
        float ninv[9];
        #pragma unroll
        for (int k = 0; k < 9; ++k) {
            int dy = k / 3 - 1, dx = k % 3 - 1;   // y_off=repeat, x_off=tile
            int ry = min(max(y + dy, 0), Hh - 1);
            int nx = min(max(px + dx, 0), Ww - 1);
            nidx[k] = ry * Ww + nx;
            ninv[k] = inv_s[side][dy + 1][nx];    // clip(y+dy)==clip(y-1+(dy+1))
        }
        const float* curp = curb + y * Ww + px;
        double acc[9] = {0,0,0,0,0,0,0,0,0};
        for (int c = 0; c < C; ++c) {
            int co = c * P;
            double xd = (double)curp[co];
            #pragma unroll
            for (int k = 0; k < 9; ++k)
                acc[k] = fma(xd, (double)sb[co + nidx[k]], acc[k]);
        }
        double best = acc[0] * (double)ninv[0];
        int bi = 0;
        #pragma unroll
        for (int k = 1; k < 9; ++k) {
            double s = acc[k] * (double)ninv[k];
            if (s < best) { best = s; bi = k; }   // strict <: first-min kept
        }
        sel_s[side][px]  = nidx[bi];
        sinv_s[side][px] = ninv[bi];
    }
    __syncthreads();

    // ---- phase 3: GEMM  O[m][j] = sum_k W[m][k] * feat(k, j), K = 768
    const int tn = t & 7;      // j-group: 8 groups of 8 columns
    const int tm = t >> 3;     // m-group: 32 groups of 8 rows
    const int rowoff = y * Ww;
    float acc[8][8] = {};

    for (int kk = 0; kk < CT; kk += 16) {
        // stage A: As[kc][m] = W[m][kk+kc]   (4096 elems, 16/thread)
        #pragma unroll
        for (int rr = 0; rr < 16; ++rr) {
            int idx = rr * 256 + t;
            int kc = idx & 15, m = idx >> 4;
            As[kc][m] = Wg[m * CT + kk + kc];
        }
        // stage B: Bs[kc][jj] = feat(kk+kc, jj)  (1024 elems, 4/thread)
        // region uniform per chunk (16 | 256)
        #pragma unroll
        for (int rr = 0; rr < 4; ++rr) {
            int idx = rr * 256 + t;
            int jj = idx & 63, kc = idx >> 6;
            float v;
            if (kk < 256)
                v = prevb[(kk + kc) * P + sel_s[0][jj]] * sinv_s[0][jj];
            else if (kk < 512)
                v = nextb[(kk + kc - 256) * P + sel_s[1][jj]] * sinv_s[1][jj];
            else
                v = curb[(kk + kc - 512) * P + rowoff + jj];
            Bs[kc][jj] = v;
        }
        __syncthreads();

        #pragma unroll
        for (int kc = 0; kc < 16; ++kc) {
            float a[8], bb[8];
            *(float4*)&a[0]  = *(const float4*)&As[kc][tm * 8];
            *(float4*)&a[4]  = *(const float4*)&As[kc][tm * 8 + 4];
            *(float4*)&bb[0] = *(const float4*)&Bs[kc][tn * 8];
            *(float4*)&bb[4] = *(const float4*)&Bs[kc][tn * 8 + 4];
            #pragma unroll
            for (int i = 0; i < 8; ++i)
                #pragma unroll
                for (int q = 0; q < 8; ++q)
                    acc[i][q] = fmaf(a[i], bb[q], acc[i][q]);
        }
        __syncthreads();
    }

    // write raw conv output to out slot 2
    float* outb = out + (size_t)(b * 3 + 2) * CP;
    #pragma unroll
    for (int i = 0; i < 8; ++i) {
        int m = tm * 8 + i;
        *(float4*)&outb[m * P + rowoff + tn * 8] =
            make_float4(acc[i][0], acc[i][1], acc[i][2], acc[i][3]);
        *(float4*)&outb[m * P + rowoff + tn * 8 + 4] =
            make_float4(acc[i][4], acc[i][5], acc[i][6], acc[i][7]);
    }
}

// ---------------------------------------------------------------------------
// Kernel 3: per-channel BN stats + normalize + ReLU, in place on out slot 2.
// One block per output channel o; block-local reduction (no atomics, no ws).
// ---------------------------------------------------------------------------
__global__ __launch_bounds__(256) void k_bn(float* __restrict__ out,
                                            const float* __restrict__ gamma,
                                            const float* __restrict__ beta) {
    __shared__ double rs[256], rq[256];
    __shared__ float sc_s, sh_s;
    const int o = blockIdx.x, t = threadIdx.x;

    double s = 0.0, q = 0.0;
    for (int b = 0; b < B; ++b) {
        const float4* base =
            (const float4*)(out + (size_t)(b * 3 + 2) * CP + (size_t)o * P);
        #pragma unroll
        for (int i = 0; i < 4; ++i) {
            float4 v = base[i * 256 + t];
            s += (double)v.x + (double)v.y + (double)v.z + (double)v.w;
            q += (double)v.x * v.x + (double)v.y * v.y
               + (double)v.z * v.z + (double)v.w * v.w;
        }
    }
    rs[t] = s; rq[t] = q;
    __syncthreads();
    for (int off = 128; off > 0; off >>= 1) {
        if (t < off) { rs[t] += rs[t + off]; rq[t] += rq[t + off]; }
        __syncthreads();
    }
    if (t == 0) {
        double mean = rs[0] * (1.0 / (double)J);
        double var  = rq[0] * (1.0 / (double)J) - mean * mean;
        double inv  = 1.0 / sqrt(var + 1e-5);
        double sc   = (double)gamma[o] * inv;
        sc_s = (float)sc;
        sh_s = (float)((double)beta[o] - mean * sc);
    }
    __syncthreads();
    const float sc = sc_s, sh = sh_s;

    for (int b = 0; b < B; ++b) {
        float4* base =
            (float4*)(out + (size_t)(b * 3 + 2) * CP + (size_t)o * P);
        #pragma unroll
        for (int i = 0; i < 4; ++i) {
            float4 v = base[i * 256 + t];
            v.x = fmaxf(fmaf(v.x, sc, sh), 0.f);
            v.y = fmaxf(fmaf(v.y, sc, sh), 0.f);
            v.z = fmaxf(fmaf(v.z, sc, sh), 0.f);
            v.w = fmaxf(fmaf(v.w, sc, sh), 0.f);
            base[i * 256 + t] = v;
        }
    }
}

// ---------------------------------------------------------------------------
extern "C" void kernel_launch(void* const* d_in, const int* in_sizes, int n_in,
                              void* d_out, int out_size, void* d_ws, size_t ws_size,
                              hipStream_t stream) {
    const float* x     = (const float*)d_in[0];
    const float* wconv = (const float*)d_in[1];
    const float* gamma = (const float*)d_in[2];
    const float* beta  = (const float*)d_in[3];
    float* out = (float*)d_out;
    (void)d_ws; (void)ws_size;   // deliberately unused

    k_copy<<<(B * 2 * CP / 4 + 255) / 256, 256, 0, stream>>>(
        (const float4*)x, (float4*)out);

    k_fused<<<B * Hh, 256, 0, stream>>>(x, wconv, out);

    k_bn<<<C, 256, 0, stream>>>(out, gamma, beta);
}

// Round 5
// 327.528 us; speedup vs baseline: 1.8253x; 1.8253x over previous
//
#include <hip/hip_runtime.h>

// Problem constants
constexpr int B  = 8;
constexpr int C  = 256;
constexpr int Hh = 64;
constexpr int Ww = 64;
constexpr int P  = Hh * Ww;        // 4096 pixels
constexpr int CP = C * P;          // elements per (b,t) slice
constexpr int CT = 3 * C;          // 768 concat channels
constexpr int J  = B * P;          // 32768 columns

// NOTE: d_ws is never touched (ws writes correlated with container crashes
// rounds 1-3). Scratch lives in out[0 .. ~300K floats) = batch-0 slot-0,
// which k_copy overwrites LAST.

typedef __attribute__((ext_vector_type(8))) short short8;
typedef __attribute__((ext_vector_type(4))) float f32x4;

__device__ inline unsigned short bf16_rne(float f) {
    unsigned u = __float_as_uint(f);
    return (unsigned short)((u + 0x7fffu + ((u >> 16) & 1u)) >> 16);
}
__device__ inline unsigned pack2(float a, float b) {
    return (unsigned)bf16_rne(a) | ((unsigned)bf16_rne(b) << 16);
}

// ---------------------------------------------------------------------------
// Kernel: convert conv weights fp32 -> bf16 (RNE), layout unchanged [m][k]
// ---------------------------------------------------------------------------
__global__ __launch_bounds__(256) void k_wcvt(const float* __restrict__ Wg,
                                              unsigned short* __restrict__ Wb) {
    int i = blockIdx.x * 256 + threadIdx.x;   // 196608 elems, grid exact
    Wb[i] = bf16_rne(Wg[i]);
}

// ---------------------------------------------------------------------------
// Kernel: inv L2 norm of every prev/next feature vector (fp64 accumulate)
// ---------------------------------------------------------------------------
__global__ __launch_bounds__(256) void k_norm(const float* __restrict__ x,
                                              float* __restrict__ invall) {
    int tid  = blockIdx.x * 256 + threadIdx.x;   // 0..65535
    int side = tid >> 15;
    int j    = tid & (J - 1);
    int b = j >> 12, p = j & (P - 1);
    const float* src = x + (size_t)(b * 3 + side) * CP + p;
    double acc = 0.0;
    #pragma unroll 8
    for (int c = 0; c < C; ++c) {
        float v = src[(size_t)c * P];
        acc = fma((double)v, (double)v, acc);
    }
    invall[side * J + j] = 1.0f / fmaxf((float)sqrt(acc), 1e-12f);
}

// ---------------------------------------------------------------------------
// Kernel: argmin cosine sim over 9 clipped neighbors (fp64 dots; common
// positive 1/|cur| dropped -> same ordering; strict < = first-min tie-break).
// Writes selected pixel index and its inv norm.
// ---------------------------------------------------------------------------
__global__ __launch_bounds__(256) void k_argmin(const float* __restrict__ x,
                                                const float* __restrict__ invall,
                                                int* __restrict__ sel,
                                                float* __restrict__ siv) {
    int j    = blockIdx.x * 256 + threadIdx.x;
    int side = blockIdx.y;
    int b = j >> 12, p = j & (P - 1);
    int y = p >> 6, xc = p & 63;

    int nidx[9];
    #pragma unroll
    for (int k = 0; k < 9; ++k) {
        int dy = k / 3 - 1, dx = k % 3 - 1;     // y_off=repeat, x_off=tile
        int yy = min(max(y + dy, 0), Hh - 1);
        int xx = min(max(xc + dx, 0), Ww - 1);
        nidx[k] = yy * Ww + xx;
    }

    const float* curp = x + (size_t)(b * 3 + 2) * CP + p;
    const float* yb   = x + (size_t)(b * 3 + side) * CP;
    const float* iv   = invall + side * J + b * P;

    double acc[9] = {0,0,0,0,0,0,0,0,0};
    for (int c = 0; c < C; ++c) {
        size_t co = (size_t)c * P;
        double xd = (double)curp[co];
        #pragma unroll
        for (int k = 0; k < 9; ++k)
            acc[k] = fma(xd, (double)yb[co + nidx[k]], acc[k]);
    }

    double best = acc[0] * (double)iv[nidx[0]];
    int bi = 0;
    #pragma unroll
    for (int k = 1; k < 9; ++k) {
        double s = acc[k] * (double)iv[nidx[k]];
        if (s < best) { best = s; bi = k; }
    }
    sel[side * J + j] = nidx[bi];
    siv[side * J + j] = iv[nidx[bi]];
}

// ---------------------------------------------------------------------------
// Kernel: bf16 MFMA GEMM with fused gather+normalize+cvt of the feature
// matrix. C[m=256][j-tile of 128] = sum_k W[m][k] * F(k,j), K = 768.
// Grid: 256 blocks (J/128), 512 threads (8 waves; wave = 64m x 64n subtile;
// 4x4 frags of mfma_f32_16x16x32_bf16).
// LDS tiles store k-octets: As[ko][m][8], Bs[ko][n][8] -> frag loads are
// single ds_read_b128 (layouts per measured m89/m91 mappings).
// Raw conv output -> out slot 2.
// ---------------------------------------------------------------------------
__global__ __launch_bounds__(512) void k_gemm(const float* __restrict__ x,
                                              const unsigned short* __restrict__ Wb,
                                              const int* __restrict__ sel,
                                              const float* __restrict__ siv,
                                              float* __restrict__ out) {
    __shared__ unsigned short As[4][256][8];   // 16 KB, k-octet blocked
    __shared__ unsigned short Bs[4][128][8];   // 8 KB
    __shared__ int   sel_s[2][128];
    __shared__ float siv_s[2][128];

    const int t  = threadIdx.x;
    const int j0 = blockIdx.x * 128;
    const int b  = j0 >> 12, p0 = j0 & (P - 1);   // 128 | 4096 -> b uniform

    if (t < 256) {
        int side = t >> 7, jj = t & 127;
        sel_s[side][jj] = sel[side * J + j0 + jj];
        siv_s[side][jj] = siv[side * J + j0 + jj];
    }
    __syncthreads();

    const float* prevb = x + (size_t)(b * 3 + 0) * CP;
    const float* nextb = x + (size_t)(b * 3 + 1) * CP;
    const float* curb  = x + (size_t)(b * 3 + 2) * CP;

    const int lane = t & 63, w = t >> 6;
    const int q = lane >> 4, l16 = lane & 15;
    const int m0w = (w & 3) * 64;      // 4 m-quadrants of 256
    const int n0w = (w >> 2) * 64;     // 2 n-halves of 128

    const int jj = t & 127, kq = (t >> 7) & 3;   // B staging role
    const int ma = t & 255, kh = t >> 8;         // A staging role

    f32x4 acc[4][4];
    #pragma unroll
    for (int f = 0; f < 4; ++f)
        #pragma unroll
        for (int g = 0; g < 4; ++g)
            acc[f][g] = (f32x4){0.f, 0.f, 0.f, 0.f};

    for (int kk = 0; kk < CT; kk += 32) {
        // --- global loads into regs (no LDS yet) ---
        const unsigned short* wsrc = Wb + (size_t)ma * CT + kk + kh * 16;
        short8 wa0 = *(const short8*)wsrc;
        short8 wa1 = *(const short8*)(wsrc + 8);

        const float* src; float scale;
        int k0 = kq * 8;
        if (kk < 256) {
            src = prevb + (size_t)(kk + k0) * P + sel_s[0][jj];
            scale = siv_s[0][jj];
        } else if (kk < 512) {
            src = nextb + (size_t)(kk - 256 + k0) * P + sel_s[1][jj];
            scale = siv_s[1][jj];
        } else {
            src = curb + (size_t)(kk - 512 + k0) * P + p0 + jj;
            scale = 1.0f;
        }
        float f0 = src[0] * scale,             f1 = src[(size_t)P] * scale;
        float f2 = src[(size_t)2 * P] * scale, f3 = src[(size_t)3 * P] * scale;
        float f4 = src[(size_t)4 * P] * scale, f5 = src[(size_t)5 * P] * scale;
        float f6 = src[(size_t)6 * P] * scale, f7 = src[(size_t)7 * P] * scale;

        __syncthreads();   // prior iteration done reading LDS

        *(short8*)&As[kh * 2    ][ma][0] = wa0;
        *(short8*)&As[kh * 2 + 1][ma][0] = wa1;
        uint4 pk = make_uint4(pack2(f0, f1), pack2(f2, f3),
                              pack2(f4, f5), pack2(f6, f7));
        *(uint4*)&Bs[kq][jj][0] = pk;

        __syncthreads();

        short8 af[4], bfr[4];
        #pragma unroll
        for (int f = 0; f < 4; ++f)
            af[f] = *(const short8*)&As[q][m0w + f * 16 + l16][0];
        #pragma unroll
        for (int g = 0; g < 4; ++g)
            bfr[g] = *(const short8*)&Bs[q][n0w + g * 16 + l16][0];
        #pragma unroll
        for (int f = 0; f < 4; ++f)
            #pragma unroll
            for (int g = 0; g < 4; ++g)
                acc[f][g] = __builtin_amdgcn_mfma_f32_16x16x32_bf16(
                    af[f], bfr[g], acc[f][g], 0, 0, 0);
    }

    // epilogue: D[row=q*4+r][col=l16] per 16x16 frag (measured C/D layout)
    float* outb = out + (size_t)(b * 3 + 2) * CP;
    #pragma unroll
    for (int f = 0; f < 4; ++f)
        #pragma unroll
        for (int g = 0; g < 4; ++g)
            #pragma unroll
            for (int r = 0; r < 4; ++r) {
                int ch  = m0w + f * 16 + q * 4 + r;
                int col = p0 + n0w + g * 16 + l16;
                outb[(size_t)ch * P + col] = acc[f][g][r];
            }
}

// ---------------------------------------------------------------------------
// Kernel: per-channel BN stats + normalize + ReLU in place on out slot 2
// (one block per channel; block-local fp64 reduction; proven round 4)
// ---------------------------------------------------------------------------
__global__ __launch_bounds__(256) void k_bn(float* __restrict__ out,
                                            const float* __restrict__ gamma,
                                            const float* __restrict__ beta) {
    __shared__ double rs[256], rq[256];
    __shared__ float sc_s, sh_s;
    const int o = blockIdx.x, t = threadIdx.x;

    double s = 0.0, q = 0.0;
    for (int b = 0; b < B; ++b) {
        const float4* base =
            (const float4*)(out + (size_t)(b * 3 + 2) * CP + (size_t)o * P);
        #pragma unroll
        for (int i = 0; i < 4; ++i) {
            float4 v = base[i * 256 + t];
            s += (double)v.x + (double)v.y + (double)v.z + (double)v.w;
            q += (double)v.x * v.x + (double)v.y * v.y
               + (double)v.z * v.z + (double)v.w * v.w;
        }
    }
    rs[t] = s; rq[t] = q;
    __syncthreads();
    for (int off = 128; off > 0; off >>= 1) {
        if (t < off) { rs[t] += rs[t + off]; rq[t] += rq[t + off]; }
        __syncthreads();
    }
    if (t == 0) {
        double mean = rs[0] * (1.0 / (double)J);
        double var  = rq[0] * (1.0 / (double)J) - mean * mean;
        double inv  = 1.0 / sqrt(var + 1e-5);
        double sc   = (double)gamma[o] * inv;
        sc_s = (float)sc;
        sh_s = (float)((double)beta[o] - mean * sc);
    }
    __syncthreads();
    const float sc = sc_s, sh = sh_s;

    for (int b = 0; b < B; ++b) {
        float4* base =
            (float4*)(out + (size_t)(b * 3 + 2) * CP + (size_t)o * P);
        #pragma unroll
        for (int i = 0; i < 4; ++i) {
            float4 v = base[i * 256 + t];
            v.x = fmaxf(fmaf(v.x, sc, sh), 0.f);
            v.y = fmaxf(fmaf(v.y, sc, sh), 0.f);
            v.z = fmaxf(fmaf(v.z, sc, sh), 0.f);
            v.w = fmaxf(fmaf(v.w, sc, sh), 0.f);
            base[i * 256 + t] = v;
        }
    }
}

// ---------------------------------------------------------------------------
// Kernel: copy prev/next slices to output slots 0/1 (runs LAST: overwrites
// the scratch region used by earlier kernels)
// ---------------------------------------------------------------------------
__global__ __launch_bounds__(256) void k_copy(const float4* __restrict__ x4,
                                              float4* __restrict__ o4) {
    int tid = blockIdx.x * blockDim.x + threadIdx.x;
    const int per_b = 2 * CP / 4;
    const int bstr  = 3 * CP / 4;
    if (tid < B * per_b) {
        int b = tid / per_b;
        int r = tid - b * per_b;
        o4[b * bstr + r] = x4[b * bstr + r];
    }
}

// ---------------------------------------------------------------------------
extern "C" void kernel_launch(void* const* d_in, const int* in_sizes, int n_in,
                              void* d_out, int out_size, void* d_ws, size_t ws_size,
                              hipStream_t stream) {
    const float* x     = (const float*)d_in[0];
    const float* wconv = (const float*)d_in[1];
    const float* gamma = (const float*)d_in[2];
    const float* beta  = (const float*)d_in[3];
    float* out = (float*)d_out;
    (void)d_ws; (void)ws_size;   // deliberately unused

    // scratch inside out batch-0 slot-0 (first CP floats), overwritten by
    // k_copy at the end:
    float*          invall = out;                                 // 2*J f
    int*            sel    = (int*)(out + 2 * J);                 // 2*J i
    float*          siv    = out + 4 * J;                         // 2*J f
    unsigned short* Wbuf   = (unsigned short*)(out + 6 * J);      // CT*C u16

    k_wcvt<<<CT * C / 256, 256, 0, stream>>>(wconv, Wbuf);

    k_norm<<<2 * J / 256, 256, 0, stream>>>(x, invall);

    k_argmin<<<dim3(J / 256, 2), 256, 0, stream>>>(x, invall, sel, siv);

    k_gemm<<<J / 128, 512, 0, stream>>>(x, Wbuf, sel, siv, out);

    k_bn<<<C, 256, 0, stream>>>(out, gamma, beta);

    k_copy<<<(B * 2 * CP / 4 + 255) / 256, 256, 0, stream>>>(
        (const float4*)x, (float4*)out);
}